// Round 1
// baseline (210.496 us; speedup 1.0000x reference)
//
#include <hip/hip_runtime.h>

// YOLOv3 loss on MI355X.
// Key insight: only channel 4 of every cell + full 85 channels at the ~<=2400
// positive cells are needed. Per-cell target reconstruction by scanning the
// 50 per-batch target records (L1-broadcast) instead of dense scatter grids.

#define NB 16      // batch
#define NT 50      // targets per batch
#define NA 3       // anchors
#define NC 80      // classes
#define CPT 4      // cells per thread in reduce

__device__ __forceinline__ float bce0(float p) { return -log1pf(-p); } // target 0
__device__ __forceinline__ float bce1(float p) { return -logf(p); }    // target 1

// ---------------- build: per-target records ----------------
__global__ __launch_bounds__(256) void build_kernel(
    const float* __restrict__ targets,
    const float* __restrict__ a13,
    const float* __restrict__ a26,
    const float* __restrict__ a52,
    unsigned* __restrict__ rec_meta,   // [3][NB*NT]
    float4*   __restrict__ rec_vals,   // [3][NB*NT]
    float*    __restrict__ acc)        // [32]
{
    int gid = blockIdx.x * blockDim.x + threadIdx.x;
    if (gid < 32) acc[gid] = 0.0f;
    if (gid >= 3 * NB * NT) return;

    int scale = gid / (NB * NT);
    int i = gid - scale * (NB * NT);       // b*NT + t
    int g = (scale == 0) ? 13 : (scale == 1) ? 26 : 52;
    const float* anch = (scale == 0) ? a13 : (scale == 1) ? a26 : a52;

    const float* tg = targets + (size_t)i * 5;
    float x1 = tg[0], y1 = tg[1], x2 = tg[2], y2 = tg[3];
    int cls = (int)tg[4];
    float gf = (float)g;
    float bx = 0.5f * (x1 + x2) * gf;
    float by = 0.5f * (y1 + y2) * gf;
    float bw = (x2 - x1) * gf;
    float bh = (y2 - y1) * gf;

    int best = 0;
    float bestiou = -1.0f, aw_b = 1.0f, ah_b = 1.0f;
    unsigned nmz = 0;  // bit a: iou[a] > 0.5 (keep==0)
    for (int a = 0; a < NA; ++a) {
        float aw = anch[a * 2 + 0], ah = anch[a * 2 + 1];
        float inter = fminf(aw, bw) * fminf(ah, bh);
        float uni = 1e-8f + aw * ah + bw * bh - inter;
        float iou = inter / uni;
        if (iou > 0.5f) nmz |= (1u << a);
        if (iou > bestiou) { bestiou = iou; best = a; aw_b = aw; ah_b = ah; } // first-max wins
    }
    int gi = (int)bx; gi = gi < 0 ? 0 : (gi > g - 1 ? g - 1 : gi);
    int gj = (int)by; gj = gj < 0 ? 0 : (gj > g - 1 ? g - 1 : gj);
    float tx = bx - floorf(bx);
    float ty = by - floorf(by);
    float tw = logf(bw / aw_b);
    float th = logf(bh / ah_b);

    unsigned meta = (unsigned)gi | ((unsigned)gj << 6) | ((unsigned)best << 12)
                  | ((unsigned)cls << 14) | (nmz << 21);
    rec_meta[scale * (NB * NT) + i] = meta;
    rec_vals[scale * (NB * NT) + i] = make_float4(tx, ty, tw, th);
}

// ---------------- reduce: one pass over all cells ----------------
template <int G>
__device__ __forceinline__ void reduce_cells(
    const float* __restrict__ out,
    const unsigned* __restrict__ metas,   // this scale's [NB*NT]
    const float4* __restrict__ vals,
    int lblk, float* s, float& npos, float& nneg)
{
    const int gg = G * G;
    const int S = NB * NA * gg;
    int base = lblk * (256 * CPT) + threadIdx.x;
    for (int k = 0; k < CPT; ++k) {
        int cell = base + k * 256;
        if (cell >= S) break;
        int b  = cell / (NA * gg);
        int r  = cell - b * (NA * gg);
        int a  = r / gg;
        int r2 = r - a * gg;
        int gj = r2 / G;
        int gi = r2 - gj * G;

        float pobj = out[(size_t)cell * 85 + 4];

        bool pos = false, zeroed = false;
        int lastt = -1;
        unsigned cb0 = 0, cb1 = 0, cb2 = 0;
        const unsigned* m = metas + b * NT;
        for (int t = 0; t < NT; ++t) {
            unsigned mt = m[t];                // wave-uniform -> L1 broadcast
            int tgi = mt & 63;
            int tgj = (mt >> 6) & 63;
            if (tgi == gi && tgj == gj) {
                int bst = (mt >> 12) & 3;
                unsigned nz = (mt >> 21) & 7;
                if (bst == a) {
                    pos = true; lastt = t;     // ascending loop -> last-write-wins
                    int c = (mt >> 14) & 127;
                    if (c < 32) cb0 |= 1u << c;
                    else if (c < 64) cb1 |= 1u << (c - 32);
                    else cb2 |= 1u << (c - 64);
                    zeroed = true;             // nm.at[b,best,gj,gi].min(0)
                }
                if ((nz >> a) & 1) zeroed = true;  // keep==0 for this anchor
            }
        }
        if (!zeroed) { nneg += 1.0f; s[5] += bce0(pobj); }
        if (pos) {
            npos += 1.0f;
            float4 v = vals[b * NT + lastt];
            const float* pc = out + (size_t)cell * 85;
            float p0 = pc[0], p1 = pc[1], p2 = pc[2], p3 = pc[3];
            s[0] += (p0 - v.x) * (p0 - v.x);
            s[1] += (p1 - v.y) * (p1 - v.y);
            s[2] += (p2 - v.z) * (p2 - v.z);
            s[3] += (p3 - v.w) * (p3 - v.w);
            s[4] += bce1(pobj);
            float cl = 0.0f;
            const float* pcl = pc + 5;
            for (int c = 0; c < NC; ++c) {
                float p = pcl[c];
                unsigned w = (c < 32) ? cb0 : (c < 64) ? cb1 : cb2;
                bool on = (w >> (c & 31)) & 1u;
                cl += on ? bce1(p) : bce0(p);
            }
            s[6] += cl;
        }
    }
}

__global__ __launch_bounds__(256) void reduce_kernel(
    const float* __restrict__ out13,
    const float* __restrict__ out26,
    const float* __restrict__ out52,
    const unsigned* __restrict__ rec_meta,
    const float4* __restrict__ rec_vals,
    float* __restrict__ acc,
    int nb0, int nb01)
{
    int blk = blockIdx.x;
    int scale, lblk;
    if (blk < nb0)       { scale = 0; lblk = blk; }
    else if (blk < nb01) { scale = 1; lblk = blk - nb0; }
    else                 { scale = 2; lblk = blk - nb01; }

    float s[7] = {0, 0, 0, 0, 0, 0, 0};
    float npos = 0.0f, nneg = 0.0f;

    if (scale == 0)      reduce_cells<13>(out13, rec_meta,            rec_vals,            lblk, s, npos, nneg);
    else if (scale == 1) reduce_cells<26>(out26, rec_meta + NB * NT,  rec_vals + NB * NT,  lblk, s, npos, nneg);
    else                 reduce_cells<52>(out52, rec_meta + 2*NB*NT,  rec_vals + 2*NB*NT,  lblk, s, npos, nneg);

    // block reduction of 9 partials
    __shared__ float red[4][9];
    int wave = threadIdx.x >> 6;
    int lane = threadIdx.x & 63;
    float v9[9] = { s[0], s[1], s[2], s[3], s[4], s[5], s[6], npos, nneg };
    #pragma unroll
    for (int j = 0; j < 9; ++j) {
        float x = v9[j];
        for (int off = 32; off; off >>= 1) x += __shfl_down(x, off);
        if (lane == 0) red[wave][j] = x;
    }
    __syncthreads();
    if (threadIdx.x < 9) {
        float x = red[0][threadIdx.x] + red[1][threadIdx.x]
                + red[2][threadIdx.x] + red[3][threadIdx.x];
        atomicAdd(&acc[scale * 10 + threadIdx.x], x);
    }
}

// ---------------- final: combine scales ----------------
__global__ void final_kernel(const float* __restrict__ acc, float* __restrict__ outp)
{
    float total = 0.0f;
    for (int sidx = 0; sidx < 3; ++sidx) {
        const float* a = acc + sidx * 10;
        float npos = a[7], nneg = a[8];
        float lx = a[0] / npos, ly = a[1] / npos, lw = a[2] / npos, lh = a[3] / npos;
        float obj = a[4] / npos;
        float noobj = a[5] / nneg * 100.0f;
        float lcls = a[6] / (npos * (float)NC);
        total += lx + ly + lw + lh + obj + noobj + lcls;
    }
    outp[0] = total;
}

extern "C" void kernel_launch(void* const* d_in, const int* in_sizes, int n_in,
                              void* d_out, int out_size, void* d_ws, size_t ws_size,
                              hipStream_t stream)
{
    const float* out13   = (const float*)d_in[0];
    const float* out26   = (const float*)d_in[1];
    const float* out52   = (const float*)d_in[2];
    const float* targets = (const float*)d_in[3];
    const float* a13     = (const float*)d_in[4];
    const float* a26     = (const float*)d_in[5];
    const float* a52     = (const float*)d_in[6];

    // ws layout: [0,128)   float acc[32]
    //            [128,9728)          rec_meta[3][800] (uint32)
    //            [9728,48128)        rec_vals[3][800] (float4)
    float*    acc      = (float*)d_ws;
    unsigned* rec_meta = (unsigned*)((char*)d_ws + 128);
    float4*   rec_vals = (float4*)((char*)d_ws + 9728);

    build_kernel<<<10, 256, 0, stream>>>(targets, a13, a26, a52, rec_meta, rec_vals, acc);

    // cells: s0=8112, s1=32448, s2=129792; 1024 cells/block
    const int nb0 = 8, nb1 = 32, nb2 = 127;
    reduce_kernel<<<nb0 + nb1 + nb2, 256, 0, stream>>>(
        out13, out26, out52, rec_meta, rec_vals, acc, nb0, nb0 + nb1);

    final_kernel<<<1, 1, 0, stream>>>(acc, (float*)d_out);
}

// Round 2
// 197.429 us; speedup vs baseline: 1.0662x; 1.0662x over previous
//
#include <hip/hip_runtime.h>

// YOLOv3 loss on MI355X — round 2.
// Structure: (1) build per-target records (2400 threads);
// (2) STREAMING noobj sum over ALL cells' channel-4 (coalesced float4, ~58MB);
// (3) correction kernel over unique target cells (adds positive terms,
//     subtracts zeroed cells' noobj contributions); (4) final combine.

#define NB 16      // batch
#define NT 50      // targets per batch
#define NA 3       // anchors
#define NC 80      // classes

__device__ __forceinline__ float bce0(float p) { return -log1pf(-p); } // target 0
__device__ __forceinline__ float bce1(float p) { return -logf(p); }    // target 1

// acc layout per scale (10 floats): 0..3 mse sums, 4 obj, 5 noobj sum,
// 6 cls, 7 n_pos, 8 n_zeroed
// ---------------- build: per-target records ----------------
__global__ __launch_bounds__(256) void build_kernel(
    const float* __restrict__ targets,
    const float* __restrict__ a13,
    const float* __restrict__ a26,
    const float* __restrict__ a52,
    unsigned* __restrict__ rec_meta,   // [3][NB*NT]
    float4*   __restrict__ rec_vals,   // [3][NB*NT]
    float*    __restrict__ acc)        // [32]
{
    int gid = blockIdx.x * blockDim.x + threadIdx.x;
    if (gid < 32) acc[gid] = 0.0f;
    if (gid >= 3 * NB * NT) return;

    int scale = gid / (NB * NT);
    int i = gid - scale * (NB * NT);       // b*NT + t
    int g = (scale == 0) ? 13 : (scale == 1) ? 26 : 52;
    const float* anch = (scale == 0) ? a13 : (scale == 1) ? a26 : a52;

    const float* tg = targets + (size_t)i * 5;
    float x1 = tg[0], y1 = tg[1], x2 = tg[2], y2 = tg[3];
    int cls = (int)tg[4];
    float gf = (float)g;
    float bx = 0.5f * (x1 + x2) * gf;
    float by = 0.5f * (y1 + y2) * gf;
    float bw = (x2 - x1) * gf;
    float bh = (y2 - y1) * gf;

    int best = 0;
    float bestiou = -1.0f, aw_b = 1.0f, ah_b = 1.0f;
    unsigned nmz = 0;  // bit a: iou[a] > 0.5 (keep==0)
    for (int a = 0; a < NA; ++a) {
        float aw = anch[a * 2 + 0], ah = anch[a * 2 + 1];
        float inter = fminf(aw, bw) * fminf(ah, bh);
        float uni = 1e-8f + aw * ah + bw * bh - inter;
        float iou = inter / uni;
        if (iou > 0.5f) nmz |= (1u << a);
        if (iou > bestiou) { bestiou = iou; best = a; aw_b = aw; ah_b = ah; } // first-max wins
    }
    int gi = (int)bx; gi = gi < 0 ? 0 : (gi > g - 1 ? g - 1 : gi);
    int gj = (int)by; gj = gj < 0 ? 0 : (gj > g - 1 ? g - 1 : gj);
    float tx = bx - floorf(bx);
    float ty = by - floorf(by);
    float tw = logf(bw / aw_b);
    float th = logf(bh / ah_b);

    unsigned meta = (unsigned)gi | ((unsigned)gj << 6) | ((unsigned)best << 12)
                  | ((unsigned)cls << 14) | (nmz << 21);
    rec_meta[scale * (NB * NT) + i] = meta;
    rec_vals[scale * (NB * NT) + i] = make_float4(tx, ty, tw, th);
}

// ---------------- streaming noobj over ALL cells ----------------
__global__ __launch_bounds__(256) void noobj_kernel(
    const float4* __restrict__ o13,
    const float4* __restrict__ o26,
    const float4* __restrict__ o52,
    float* __restrict__ acc)
{
    const int C0 = 172380, C01 = 861900, CT = 3619980;  // float4 counts
    float s0 = 0.0f, s1 = 0.0f, s2 = 0.0f;
    for (int idx = blockIdx.x * 256 + threadIdx.x; idx < CT; idx += gridDim.x * 256) {
        int scale, li;
        const float4* p;
        if (idx < C0)       { scale = 0; li = idx;       p = o13; }
        else if (idx < C01) { scale = 1; li = idx - C0;  p = o26; }
        else                { scale = 2; li = idx - C01; p = o52; }
        float4 v = p[li];
        int r = (li * 4) % 85;       // channel of element 0
        int k = 4 - r;               // which of the 4 elements is channel 4
        if (k >= 0 && k <= 3) {
            float pv = (k == 0) ? v.x : (k == 1) ? v.y : (k == 2) ? v.z : v.w;
            float bv = bce0(pv);
            if (scale == 0) s0 += bv; else if (scale == 1) s1 += bv; else s2 += bv;
        }
    }
    __shared__ float red[4][3];
    int wave = threadIdx.x >> 6, lane = threadIdx.x & 63;
    float v3[3] = { s0, s1, s2 };
    #pragma unroll
    for (int j = 0; j < 3; ++j) {
        float x = v3[j];
        for (int off = 32; off; off >>= 1) x += __shfl_down(x, off);
        if (lane == 0) red[wave][j] = x;
    }
    __syncthreads();
    if (threadIdx.x < 3) {
        float x = red[0][threadIdx.x] + red[1][threadIdx.x]
                + red[2][threadIdx.x] + red[3][threadIdx.x];
        atomicAdd(&acc[threadIdx.x * 10 + 5], x);
    }
}

// ---------------- corrections at unique target cells ----------------
__global__ __launch_bounds__(256) void correct_kernel(
    const float* __restrict__ o13,
    const float* __restrict__ o26,
    const float* __restrict__ o52,
    const unsigned* __restrict__ rec_meta,
    const float4* __restrict__ rec_vals,
    float* __restrict__ acc)
{
    int scale = blockIdx.x >> 2;                       // 4 blocks per scale
    int lid = (blockIdx.x & 3) * 256 + threadIdx.x;    // 0..1023 within scale

    float s[9] = {0, 0, 0, 0, 0, 0, 0, 0, 0};          // constant-indexed only

    if (lid < NB * NT) {
        int b = lid / NT, t = lid - b * NT;
        const unsigned* m = rec_meta + scale * (NB * NT) + b * NT;
        const float4* vals = rec_vals + scale * (NB * NT) + b * NT;
        unsigned meta = m[t];
        unsigned key = meta & 0xFFFu;                  // gi | gj<<6
        bool canon = true;
        for (int u = 0; u < t; ++u)
            if ((m[u] & 0xFFFu) == key) { canon = false; break; }
        if (canon) {
            int G = (scale == 0) ? 13 : (scale == 1) ? 26 : 52;
            const float* out = (scale == 0) ? o13 : (scale == 1) ? o26 : o52;
            int gi = key & 63, gj = (key >> 6) & 63;

            unsigned zerobits = 0;
            for (int u = 0; u < NT; ++u) {
                unsigned mt = m[u];
                if ((mt & 0xFFFu) == key)
                    zerobits |= ((mt >> 21) & 7u) | (1u << ((mt >> 12) & 3u));
            }
            #pragma unroll
            for (int a = 0; a < NA; ++a) {
                bool pos = false;
                int lastt = 0;
                unsigned c0 = 0, c1 = 0, c2 = 0;
                for (int u = 0; u < NT; ++u) {
                    unsigned mt = m[u];
                    if ((mt & 0xFFFu) == key && (int)((mt >> 12) & 3u) == a) {
                        pos = true; lastt = u;         // ascending -> last-write-wins
                        int c = (mt >> 14) & 127;
                        if (c < 32) c0 |= 1u << c;
                        else if (c < 64) c1 |= 1u << (c - 32);
                        else c2 |= 1u << (c - 64);
                    }
                }
                size_t cell = (((size_t)(b * NA + a) * G + gj) * G + gi);
                const float* pc = out + cell * 85;
                if ((zerobits >> a) & 1u) {            // this cell's nm == 0
                    s[5] -= bce0(pc[4]);
                    s[8] += 1.0f;
                }
                if (pos) {
                    s[7] += 1.0f;
                    float4 v = vals[lastt];
                    float p0 = pc[0], p1 = pc[1], p2 = pc[2], p3 = pc[3];
                    s[0] += (p0 - v.x) * (p0 - v.x);
                    s[1] += (p1 - v.y) * (p1 - v.y);
                    s[2] += (p2 - v.z) * (p2 - v.z);
                    s[3] += (p3 - v.w) * (p3 - v.w);
                    s[4] += bce1(pc[4]);
                    float cl = 0.0f;
                    for (int c = 0; c < NC; ++c) {
                        float p = pc[5 + c];
                        unsigned w = (c < 32) ? c0 : (c < 64) ? c1 : c2;
                        cl += ((w >> (c & 31)) & 1u) ? bce1(p) : bce0(p);
                    }
                    s[6] += cl;
                }
            }
        }
    }

    __shared__ float red[4][9];
    int wave = threadIdx.x >> 6, lane = threadIdx.x & 63;
    #pragma unroll
    for (int j = 0; j < 9; ++j) {
        float x = s[j];
        for (int off = 32; off; off >>= 1) x += __shfl_down(x, off);
        if (lane == 0) red[wave][j] = x;
    }
    __syncthreads();
    if (threadIdx.x < 9) {
        float x = red[0][threadIdx.x] + red[1][threadIdx.x]
                + red[2][threadIdx.x] + red[3][threadIdx.x];
        atomicAdd(&acc[scale * 10 + threadIdx.x], x);
    }
}

// ---------------- final: combine scales ----------------
__global__ void final_kernel(const float* __restrict__ acc, float* __restrict__ outp)
{
    const float Stot[3] = { 8112.0f, 32448.0f, 129792.0f };  // B*A*g*g
    float total = 0.0f;
    for (int sidx = 0; sidx < 3; ++sidx) {
        const float* a = acc + sidx * 10;
        float npos = a[7];
        float nneg = Stot[sidx] - a[8];
        float lx = a[0] / npos, ly = a[1] / npos, lw = a[2] / npos, lh = a[3] / npos;
        float obj = a[4] / npos;
        float noobj = a[5] / nneg * 100.0f;
        float lcls = a[6] / (npos * (float)NC);
        total += lx + ly + lw + lh + obj + noobj + lcls;
    }
    outp[0] = total;
}

extern "C" void kernel_launch(void* const* d_in, const int* in_sizes, int n_in,
                              void* d_out, int out_size, void* d_ws, size_t ws_size,
                              hipStream_t stream)
{
    const float* out13   = (const float*)d_in[0];
    const float* out26   = (const float*)d_in[1];
    const float* out52   = (const float*)d_in[2];
    const float* targets = (const float*)d_in[3];
    const float* a13     = (const float*)d_in[4];
    const float* a26     = (const float*)d_in[5];
    const float* a52     = (const float*)d_in[6];

    // ws layout: [0,128)  float acc[32]
    //            [128,9728)   rec_meta[3][800] (uint32)
    //            [9728,48128) rec_vals[3][800] (float4)
    float*    acc      = (float*)d_ws;
    unsigned* rec_meta = (unsigned*)((char*)d_ws + 128);
    float4*   rec_vals = (float4*)((char*)d_ws + 9728);

    build_kernel<<<10, 256, 0, stream>>>(targets, a13, a26, a52, rec_meta, rec_vals, acc);

    noobj_kernel<<<2048, 256, 0, stream>>>(
        (const float4*)out13, (const float4*)out26, (const float4*)out52, acc);

    correct_kernel<<<12, 256, 0, stream>>>(out13, out26, out52, rec_meta, rec_vals, acc);

    final_kernel<<<1, 1, 0, stream>>>(acc, (float*)d_out);
}

// Round 3
// 32.866 us; speedup vs baseline: 6.4048x; 6.0072x over previous
//
#include <hip/hip_runtime.h>

// YOLOv3 loss on MI355X — round 3.
// (1) build per-target records (2400 threads);
// (2) noobj: gather channel-4 of every cell, one cell/thread (L3-resident);
// (3) correct: ONE WAVE per (scale,b,t); metas live in lanes, ballots/shuffles
//     replace serial scans; coalesced 85-channel gather + lane-parallel cls BCE;
// (4) final combine.

#define NB 16      // batch
#define NT 50      // targets per batch
#define NA 3       // anchors
#define NC 80      // classes

__device__ __forceinline__ float bce0(float p) { return -log1pf(-p); } // target 0
__device__ __forceinline__ float bce1(float p) { return -logf(p); }    // target 1

// acc layout per scale (10 floats): 0..3 mse sums, 4 obj, 5 noobj sum,
// 6 cls, 7 n_pos, 8 n_zeroed

// ---------------- build: per-target records ----------------
__global__ __launch_bounds__(256) void build_kernel(
    const float* __restrict__ targets,
    const float* __restrict__ a13,
    const float* __restrict__ a26,
    const float* __restrict__ a52,
    unsigned* __restrict__ rec_meta,   // [3][NB*NT]
    float4*   __restrict__ rec_vals,   // [3][NB*NT]
    float*    __restrict__ acc)        // [32]
{
    int gid = blockIdx.x * blockDim.x + threadIdx.x;
    if (gid < 32) acc[gid] = 0.0f;
    if (gid >= 3 * NB * NT) return;

    int scale = gid / (NB * NT);
    int i = gid - scale * (NB * NT);       // b*NT + t
    int g = (scale == 0) ? 13 : (scale == 1) ? 26 : 52;
    const float* anch = (scale == 0) ? a13 : (scale == 1) ? a26 : a52;

    const float* tg = targets + (size_t)i * 5;
    float x1 = tg[0], y1 = tg[1], x2 = tg[2], y2 = tg[3];
    int cls = (int)tg[4];
    float gf = (float)g;
    float bx = 0.5f * (x1 + x2) * gf;
    float by = 0.5f * (y1 + y2) * gf;
    float bw = (x2 - x1) * gf;
    float bh = (y2 - y1) * gf;

    int best = 0;
    float bestiou = -1.0f, aw_b = 1.0f, ah_b = 1.0f;
    unsigned nmz = 0;  // bit a: iou[a] > 0.5 (keep==0)
    for (int a = 0; a < NA; ++a) {
        float aw = anch[a * 2 + 0], ah = anch[a * 2 + 1];
        float inter = fminf(aw, bw) * fminf(ah, bh);
        float uni = 1e-8f + aw * ah + bw * bh - inter;
        float iou = inter / uni;
        if (iou > 0.5f) nmz |= (1u << a);
        if (iou > bestiou) { bestiou = iou; best = a; aw_b = aw; ah_b = ah; } // first-max wins
    }
    int gi = (int)bx; gi = gi < 0 ? 0 : (gi > g - 1 ? g - 1 : gi);
    int gj = (int)by; gj = gj < 0 ? 0 : (gj > g - 1 ? g - 1 : gj);
    float tx = bx - floorf(bx);
    float ty = by - floorf(by);
    float tw = logf(bw / aw_b);
    float th = logf(bh / ah_b);

    unsigned meta = (unsigned)gi | ((unsigned)gj << 6) | ((unsigned)best << 12)
                  | ((unsigned)cls << 14) | (nmz << 21);
    rec_meta[scale * (NB * NT) + i] = meta;
    rec_vals[scale * (NB * NT) + i] = make_float4(tx, ty, tw, th);
}

// ---------------- noobj: gather channel 4 of every cell ----------------
__global__ __launch_bounds__(256) void noobj_kernel(
    const float* __restrict__ o13,
    const float* __restrict__ o26,
    const float* __restrict__ o52,
    float* __restrict__ acc)
{
    const int C0 = 8112, C01 = 40560, CT = 170352;   // cell boundaries
    int idx = blockIdx.x * 256 + threadIdx.x;
    float s0 = 0.0f, s1 = 0.0f, s2 = 0.0f;
    if (idx < CT) {
        const float* p; int li, scale;
        if (idx < C0)       { p = o13; li = idx;       scale = 0; }
        else if (idx < C01) { p = o26; li = idx - C0;  scale = 1; }
        else                { p = o52; li = idx - C01; scale = 2; }
        float bv = bce0(p[(size_t)li * 85 + 4]);
        if (scale == 0) s0 = bv; else if (scale == 1) s1 = bv; else s2 = bv;
    }
    __shared__ float red[4][3];
    int wave = threadIdx.x >> 6, lane = threadIdx.x & 63;
    float v3[3] = { s0, s1, s2 };
    #pragma unroll
    for (int j = 0; j < 3; ++j) {
        float x = v3[j];
        for (int off = 32; off; off >>= 1) x += __shfl_down(x, off);
        if (lane == 0) red[wave][j] = x;
    }
    __syncthreads();
    if (threadIdx.x < 3) {
        float x = red[0][threadIdx.x] + red[1][threadIdx.x]
                + red[2][threadIdx.x] + red[3][threadIdx.x];
        atomicAdd(&acc[threadIdx.x * 10 + 5], x);
    }
}

// ---------------- correct: one wave per (scale,b,t) ----------------
__global__ __launch_bounds__(256) void correct_kernel(
    const float* __restrict__ o13,
    const float* __restrict__ o26,
    const float* __restrict__ o52,
    const unsigned* __restrict__ rec_meta,
    const float4* __restrict__ rec_vals,
    float* __restrict__ acc)
{
    __shared__ float sacc[27];
    if (threadIdx.x < 27) sacc[threadIdx.x] = 0.0f;
    __syncthreads();

    int wid  = blockIdx.x * 4 + (threadIdx.x >> 6);   // 0..2399
    int lane = threadIdx.x & 63;
    int scale = wid / (NB * NT);
    int rem   = wid - scale * (NB * NT);
    int b = rem / NT, t = rem - b * NT;

    int G = (scale == 0) ? 13 : (scale == 1) ? 26 : 52;
    const float* out = (scale == 0) ? o13 : (scale == 1) ? o26 : o52;
    const unsigned* m = rec_meta + scale * (NB * NT) + b * NT;
    const float4* vb  = rec_vals + scale * (NB * NT) + b * NT;

    unsigned mt = (lane < NT) ? m[lane] : 0xFFFFFFFFu;  // coalesced, one load/lane
    unsigned key_lane = mt & 0xFFFu;
    unsigned key_t = __shfl(key_lane, t);
    unsigned long long match = __ballot(lane < NT && key_lane == key_t);
    bool canon = ((match & ((1ull << t) - 1ull)) == 0ull);  // wave-uniform

    if (canon) {
        int gi = key_t & 63, gj = (key_t >> 6) & 63;
        #pragma unroll
        for (int a = 0; a < NA; ++a) {
            unsigned long long bestmask =
                __ballot(lane < NT && key_lane == key_t && (int)((mt >> 12) & 3u) == a);
            unsigned long long nmzmask =
                __ballot(lane < NT && key_lane == key_t && ((mt >> (21 + a)) & 1u));
            bool pos = bestmask != 0ull;
            bool zeroed = pos || (nmzmask != 0ull);
            if (!zeroed) continue;                      // wave-uniform

            const float* pc = out + (((size_t)(b * NA + a) * G + gj) * G + gi) * 85;
            float vlo = pc[lane];                       // channels 0..63, coalesced
            if (lane == 4) {                            // noobj correction
                atomicAdd(&sacc[scale * 9 + 5], -bce0(vlo));
                atomicAdd(&sacc[scale * 9 + 8], 1.0f);
            }
            if (pos) {
                float vhi = (lane < 21) ? pc[64 + lane] : 0.0f;  // channels 64..84
                int lastt = 63 - __clzll(bestmask);     // last-write-wins
                // class-bit union across matching-best lanes (96-bit OR butterfly)
                unsigned c0 = 0, c1 = 0, c2 = 0;
                if ((bestmask >> lane) & 1ull) {
                    int c = (mt >> 14) & 127;
                    if (c < 32) c0 = 1u << c;
                    else if (c < 64) c1 = 1u << (c - 32);
                    else c2 = 1u << (c - 64);
                }
                #pragma unroll
                for (int off = 32; off; off >>= 1) {
                    c0 |= __shfl_xor(c0, off);
                    c1 |= __shfl_xor(c1, off);
                    c2 |= __shfl_xor(c2, off);
                }
                // lane-parallel class BCE: lane handles channel (lane) and (64+lane)
                float cls = 0.0f;
                if (lane >= 5) {
                    int c = lane - 5;                   // 0..58
                    unsigned w = (c < 32) ? c0 : c1;
                    cls += ((w >> (c & 31)) & 1u) ? bce1(vlo) : bce0(vlo);
                }
                if (lane < 21) {
                    int c = lane + 59;                  // 59..79
                    unsigned w = (c < 64) ? c1 : c2;
                    cls += ((w >> (c & 31)) & 1u) ? bce1(vhi) : bce0(vhi);
                }
                #pragma unroll
                for (int off = 32; off; off >>= 1) cls += __shfl_xor(cls, off);
                if (lane == 0) {
                    atomicAdd(&sacc[scale * 9 + 6], cls);
                    atomicAdd(&sacc[scale * 9 + 7], 1.0f);
                }
                if (lane < 4) {                         // mse terms
                    float tv = ((const float*)vb)[lastt * 4 + lane];
                    float d = vlo - tv;
                    atomicAdd(&sacc[scale * 9 + lane], d * d);
                }
                if (lane == 4) atomicAdd(&sacc[scale * 9 + 4], bce1(vlo));
            }
        }
    }
    __syncthreads();
    if (threadIdx.x < 27) {
        float v = sacc[threadIdx.x];
        if (v != 0.0f)
            atomicAdd(&acc[(threadIdx.x / 9) * 10 + (threadIdx.x % 9)], v);
    }
}

// ---------------- final: combine scales ----------------
__global__ void final_kernel(const float* __restrict__ acc, float* __restrict__ outp)
{
    const float Stot[3] = { 8112.0f, 32448.0f, 129792.0f };  // B*A*g*g
    float total = 0.0f;
    for (int sidx = 0; sidx < 3; ++sidx) {
        const float* a = acc + sidx * 10;
        float npos = a[7];
        float nneg = Stot[sidx] - a[8];
        float lx = a[0] / npos, ly = a[1] / npos, lw = a[2] / npos, lh = a[3] / npos;
        float obj = a[4] / npos;
        float noobj = a[5] / nneg * 100.0f;
        float lcls = a[6] / (npos * (float)NC);
        total += lx + ly + lw + lh + obj + noobj + lcls;
    }
    outp[0] = total;
}

extern "C" void kernel_launch(void* const* d_in, const int* in_sizes, int n_in,
                              void* d_out, int out_size, void* d_ws, size_t ws_size,
                              hipStream_t stream)
{
    const float* out13   = (const float*)d_in[0];
    const float* out26   = (const float*)d_in[1];
    const float* out52   = (const float*)d_in[2];
    const float* targets = (const float*)d_in[3];
    const float* a13     = (const float*)d_in[4];
    const float* a26     = (const float*)d_in[5];
    const float* a52     = (const float*)d_in[6];

    // ws layout: [0,128)  float acc[32]
    //            [128,9728)   rec_meta[3][800] (uint32)
    //            [9728,48128) rec_vals[3][800] (float4)
    float*    acc      = (float*)d_ws;
    unsigned* rec_meta = (unsigned*)((char*)d_ws + 128);
    float4*   rec_vals = (float4*)((char*)d_ws + 9728);

    build_kernel<<<10, 256, 0, stream>>>(targets, a13, a26, a52, rec_meta, rec_vals, acc);

    noobj_kernel<<<666, 256, 0, stream>>>(out13, out26, out52, acc);  // 170352 cells

    correct_kernel<<<600, 256, 0, stream>>>(out13, out26, out52, rec_meta, rec_vals, acc);

    final_kernel<<<1, 1, 0, stream>>>(acc, (float*)d_out);
}